// Round 5
// baseline (256.961 us; speedup 1.0000x reference)
//
#include <hip/hip_runtime.h>
#include <hip/hip_bf16.h>
#include <stdint.h>

#define NB    2048
#define NSENT 20
#define SEC   40
#define DD    100
#define UU    50
#define SP1   801
#define ROWB  272            // bytes per LDS h row (136 shorts), 16B-aligned
#define HBUFB (64 * ROWB)    // 17408 B per buffer (32B-aligned)

typedef short bf16x8 __attribute__((ext_vector_type(8)));
typedef short bf16x4 __attribute__((ext_vector_type(4)));
typedef float f32x16 __attribute__((ext_vector_type(16)));

__device__ __forceinline__ unsigned f2bf(float f) {
  unsigned u = __float_as_uint(f);
  return (u + 0x7fffu + ((u >> 16) & 1u)) >> 16;   // RNE
}

__device__ __forceinline__ void cvt8(float4 a, float4 b, unsigned* o) {
  asm("v_cvt_pk_bf16_f32 %0, %1, %2" : "=v"(o[0]) : "v"(a.x), "v"(a.y));
  asm("v_cvt_pk_bf16_f32 %0, %1, %2" : "=v"(o[1]) : "v"(a.z), "v"(a.w));
  asm("v_cvt_pk_bf16_f32 %0, %1, %2" : "=v"(o[2]) : "v"(b.x), "v"(b.y));
  asm("v_cvt_pk_bf16_f32 %0, %1, %2" : "=v"(o[3]) : "v"(b.z), "v"(b.w));
}

// XOR swizzle key for a semantic row (bits 3,4 of byte addr; octet
// boundaries are 32B-aligned since 8*ROWB = 2176 % 32 == 0 -> bijective)
#define KEY(row) ((((row) >> 3) & 3) << 3)

// One 4-wave block per document b. Wave w = (ut = w&1, st = w>>1) owns
// C[u-tile ut][s-tile st] of C = wh . h^T (+ wub via K-bias column).
__global__ __launch_bounds__(256, 4) void doc_kernel(
    const float* __restrict__ inputs, const float* __restrict__ vw,
    const float* __restrict__ wh, const float* __restrict__ wu,
    const float* __restrict__ bw, float* __restrict__ out) {
  __shared__ __align__(16) unsigned char hsb[2 * HBUFB];  // bf16 h tiles (dbuf)
  __shared__ __align__(16) float epartf[64 * 2];          // [s][ut]
  __shared__ __align__(16) float opartf[50 * 10];         // [dpair][5 float2 slots]

  const int tid = threadIdx.x;
  const int w = tid >> 6, lane = tid & 63;
  const int ut = w & 1, st = w >> 1;
  const int l31 = lane & 31, hh = lane >> 5;
  const int b = blockIdx.x;

  const float4* base4 = (const float4*)(inputs + (size_t)b * SP1 * DD);

  // ---- issue tile-0 loads immediately (registers; span barriers freely) ----
  float4 stage[4];
  #pragma unroll
  for (int j = 0; j < 4; ++j) {
    int idx = j * 256 + tid;
    if (idx < 1000) stage[j] = base4[idx];
  }

  // ---- zero both h buffers (pad rows 40..63, K-pad cols persist) ----
  {
    uint4 z; z.x = z.y = z.z = z.w = 0u;
    uint4* p = (uint4*)hsb;
    #pragma unroll 1
    for (int i = tid; i < 2 * HBUFB / 16; i += 256) p[i] = z;
  }

  // ---- convert-pass addresses (fixed per thread) ----
  int cvta[4];
  #pragma unroll
  for (int j = 0; j < 4; ++j) {
    int idx = j * 256 + tid;
    int row = idx / 25, c4 = idx - row * 25;
    cvta[j] = (row * ROWB + c4 * 8) ^ KEY(row);
  }

  // ---- wub_u for this lane's A row: u = l31 + 32*ut ----
  const int u = l31 + 32 * ut;
  float wubv = 0.f;
  if (u < UU) {
    const float4* uv4 = (const float4*)(inputs + ((size_t)b * SP1 + SP1 - 1) * DD);
    const float4* wr4 = (const float4*)(wu + u * DD);
    float a0 = bw[u];
    #pragma unroll 5
    for (int q = 0; q < 25; ++q) {
      float4 uq = uv4[q], wq = wr4[q];
      a0 = fmaf(uq.x, wq.x, a0); a0 = fmaf(uq.y, wq.y, a0);
      a0 = fmaf(uq.z, wq.z, a0); a0 = fmaf(uq.w, wq.w, a0);
    }
    wubv = a0;
  }

  // ---- A fragments (wh rows, bf16, zero-padded, + wub bias at k=100) ----
  bf16x8 afrag[8];
  #pragma unroll
  for (int kt = 0; kt < 8; ++kt) {
    int k0 = 16 * kt + 8 * hh;
    float4 fa = {0.f,0.f,0.f,0.f}, fb = {0.f,0.f,0.f,0.f};
    if (u < UU) {
      if (k0 + 3 <= 99) fa = *(const float4*)(wh + u * DD + k0);
      if (k0 + 7 <= 99) fb = *(const float4*)(wh + u * DD + k0 + 4);
    }
    union { unsigned uu[4]; bf16x8 v; } r;
    cvt8(fa, fb, r.uu);
    if (kt == 6 && hh == 0 && u < UU) {
      union { unsigned short s[8]; bf16x8 v; } t2; t2.v = r.v;
      t2.s[4] = (unsigned short)f2bf(wubv);   // k = 100 bias column
      r.v = t2.v;
    }
    afrag[kt] = r.v;
  }

  // ---- vw for this lane's 16 accumulator rows ----
  float vwr[16];
  #pragma unroll
  for (int i = 0; i < 16; ++i) {
    int row = (i & 3) + 8 * (i >> 2) + 4 * hh;
    int ui = 32 * ut + row;
    vwr[i] = (ui < UU) ? vw[ui] : 0.f;
  }

  // ---- bias column h[s][100] = 1.0 for real s, both buffers ----
  if (tid < 80) {
    int buf = tid / SEC, s = tid - buf * SEC;
    int byte = buf * HBUFB + ((s * ROWB + 200) ^ KEY(s));
    *(unsigned short*)(hsb + byte) = 0x3F80;
  }
  __syncthreads();   // B0: zeros + bias visible

  // per-lane B-frag base (row fixed: row = l31 + 32*st)
  const int brow = l31 + 32 * st;
  const int brb = brow * ROWB, bkey = KEY(brow);

  float* outb = out + (size_t)b * NSENT * DD;

  #pragma unroll 1
  for (int t = 0; t < NSENT; ++t) {
    unsigned char* hcur = hsb + (t & 1) * HBUFB;

    // ---- convert tile t (stage regs) -> bf16 LDS ----
    #pragma unroll
    for (int j = 0; j < 4; ++j) {
      int idx = j * 256 + tid;
      if (idx < 1000) {
        unsigned o[4];
        cvt8(make_float4(stage[j].x, stage[j].y, stage[j].z, stage[j].w),
             make_float4(0.f,0.f,0.f,0.f), o);
        uint2 wv; wv.x = o[0]; wv.y = o[1];
        *(uint2*)(hcur + cvta[j]) = wv;
      }
    }
    __syncthreads();   // B1

    // ---- issue tile t+1 loads (regs), pinned before compute ----
    if (t + 1 < NSENT) {
      const float4* nb4 = base4 + (size_t)(t + 1) * 1000;
      #pragma unroll
      for (int j = 0; j < 4; ++j) {
        int idx = j * 256 + tid;
        if (idx < 1000) stage[j] = nb4[idx];
      }
    }
    __builtin_amdgcn_sched_barrier(0);

    // ---- MFMA: acc = C[u-tile ut][s-tile st], K = 128 (incl bias col) ----
    f32x16 acc = {0.f,0.f,0.f,0.f,0.f,0.f,0.f,0.f,0.f,0.f,0.f,0.f,0.f,0.f,0.f,0.f};
    #pragma unroll
    for (int kt = 0; kt < 8; ++kt) {
      int x = 32 * kt + 16 * hh;
      bf16x4 lo = *(const bf16x4*)(hcur + ((brb + x) ^ bkey));
      bf16x4 hi = *(const bf16x4*)(hcur + ((brb + x + 8) ^ bkey));
      bf16x8 bf = __builtin_shufflevector(lo, hi, 0,1,2,3,4,5,6,7);
      acc = __builtin_amdgcn_mfma_f32_32x32x16_bf16(afrag[kt], bf, acc, 0, 0, 0);
    }

    // ---- e-partial: sum over this lane's 16 u rows (in-register!) ----
    float ep = 0.f;
    #pragma unroll
    for (int i = 0; i < 16; ++i) {
      float E = exp2f(acc[i] * 2.885390081777927f);   // e^{2x}
      float tt = 1.f - 2.f * __builtin_amdgcn_rcpf(E + 1.f);
      ep = fmaf(tt, vwr[i], ep);
    }
    ep += __shfl_xor(ep, 32);                          // merge u-halves
    if (lane < 32)
      epartf[(32 * st + l31) * 2 + ut] = ep;
    __syncthreads();   // B2

    // ---- softmax over s<40 (redundant per wave; no max pass, |e|<~3) ----
    float2 e2 = (lane < SEC) ? *(const float2*)&epartf[2 * lane]
                             : make_float2(0.f, 0.f);
    float p = (lane < SEC) ? __expf(e2.x + e2.y) : 0.f;
    float sum = p;
    sum += __shfl_xor(sum, 1);
    sum += __shfl_xor(sum, 2);
    sum += __shfl_xor(sum, 4);
    sum += __shfl_xor(sum, 8);
    sum += __shfl_xor(sum, 16);
    sum += __shfl_xor(sum, 32);
    float pr = p * __builtin_amdgcn_rcpf(sum);         // alpha in lane s

    // ---- out partial: wave w sums s in [10w,10w+10); lane = d-pair ----
    if (lane < 50) {
      float f0 = 0.f, f1 = 0.f;
      #pragma unroll
      for (int i = 0; i < 10; ++i) {
        int s = 10 * w + i;
        float a = __shfl(pr, s);
        unsigned hv = *(const unsigned*)(hcur + ((s * ROWB + 4 * lane) ^ KEY(s)));
        f0 = fmaf(a, __uint_as_float(hv << 16), f0);
        f1 = fmaf(a, __uint_as_float(hv & 0xffff0000u), f1);
      }
      *(float2*)&opartf[lane * 10 + w * 2] = make_float2(f0, f1);
    }
    __syncthreads();   // B3

    if (w == 0 && lane < 50) {
      const float2* op = (const float2*)&opartf[lane * 10];
      float2 o0 = op[0], o1 = op[1], o2 = op[2], o3 = op[3];
      float2 o;
      o.x = (o0.x + o1.x) + (o2.x + o3.x);
      o.y = (o0.y + o1.y) + (o2.y + o3.y);
      *(float2*)(outb + t * DD + 2 * lane) = o;
    }
  }
}

extern "C" void kernel_launch(void* const* d_in, const int* in_sizes, int n_in,
                              void* d_out, int out_size, void* d_ws, size_t ws_size,
                              hipStream_t stream) {
  const float* inputs = (const float*)d_in[0];
  const float* vw     = (const float*)d_in[1];
  const float* wh     = (const float*)d_in[2];
  const float* wu     = (const float*)d_in[3];
  const float* bw     = (const float*)d_in[4];
  float* out = (float*)d_out;

  doc_kernel<<<NB, 256, 0, stream>>>(inputs, vw, wh, wu, bw, out);
}

// Round 7
// 171.832 us; speedup vs baseline: 1.4954x; 1.4954x over previous
//
#include <hip/hip_runtime.h>
#include <hip/hip_bf16.h>
#include <stdint.h>

#define NB    2048
#define NSENT 20
#define SEC   40
#define DD    100
#define UU    50
#define SP1   801
#define STRIDE 136   // shorts per LDS h row; 272 B

typedef short bf16x8 __attribute__((ext_vector_type(8)));
typedef float f32x4 __attribute__((ext_vector_type(4)));

__device__ __forceinline__ unsigned f2bf(float f) {
  unsigned u = __float_as_uint(f);
  return (u + 0x7fffu + ((u >> 16) & 1u)) >> 16;   // RNE
}

// One 4-wave block per document b (R3 structure). Wave w owns u-tile w of
// C[u][s] = wh . h^T. Register staging, dbuf LDS, 2 barriers/tile.
__global__ __launch_bounds__(256, 5) void doc_kernel(
    const float* __restrict__ inputs, const float* __restrict__ vw,
    const float* __restrict__ wh, const float* __restrict__ wu,
    const float* __restrict__ bw, float* __restrict__ out) {
  __shared__ __align__(16) unsigned short hs[2][48 * STRIDE]; // bf16 h tiles
  __shared__ __align__(16) float epart[3 * 16 * 4];           // [st][col][w]

  const int tid  = threadIdx.x;
  const int w    = tid >> 6, lane = tid & 63;
  const int col  = lane & 15, grp = lane >> 4;
  const int b    = blockIdx.x;

  const float4* base4 = (const float4*)(inputs + (size_t)b * SP1 * DD);

  // ---- issue tile-0 loads immediately (registers; span barriers freely) ----
  float4 stage[4];
  #pragma unroll
  for (int j = 0; j < 4; ++j) {
    int idx = j * 256 + tid;
    if (idx < 1000) stage[j] = base4[idx];
  }

  // ---- zero both h buffers once (K-pad cols + pad rows 40..47 persist) ----
  {
    uint4 z; z.x = z.y = z.z = z.w = 0u;
    uint4* p = (uint4*)&hs[0][0];
    #pragma unroll 1
    for (int i = tid; i < 2 * 48 * STRIDE / 8; i += 256) p[i] = z;
  }

  // ---- convert-pass byte addresses (fixed per thread) ----
  int cvta[4];
  #pragma unroll
  for (int j = 0; j < 4; ++j) {
    int idx = j * 256 + tid;
    int row = idx / 25, c4 = idx - row * 25;
    cvta[j] = row * 272 + c4 * 8;
  }

  // ---- A fragments: this wave's 16 wh rows (u = 16w + col), resident ----
  bf16x8 afrag[4];
  {
    int u = w * 16 + col;
    #pragma unroll
    for (int kt = 0; kt < 4; ++kt) {
      bf16x8 f;
      #pragma unroll
      for (int j = 0; j < 8; ++j) {
        int k = kt * 32 + grp * 8 + j;
        float v = (u < UU && k < DD) ? wh[u * DD + k] : 0.f;
        f[j] = (short)f2bf(v);
      }
      afrag[kt] = f;
    }
  }

  // ---- wub[u=lane] = uvec[b]·wu[u] + bw[u] (each wave redundantly) ----
  float wubacc;
  {
    int ur = lane < UU ? lane : UU - 1;
    const float4* uv4 = (const float4*)(inputs + ((size_t)b * SP1 + SP1 - 1) * DD);
    const float4* wr4 = (const float4*)(wu + ur * DD);
    float a0 = bw[ur];
    #pragma unroll 5
    for (int q = 0; q < 25; ++q) {
      float4 uq = uv4[q], wq = wr4[q];
      a0 = fmaf(uq.x, wq.x, a0); a0 = fmaf(uq.y, wq.y, a0);
      a0 = fmaf(uq.z, wq.z, a0); a0 = fmaf(uq.w, wq.w, a0);
    }
    wubacc = a0;
  }
  float vwr[4], wubr[4];
  #pragma unroll
  for (int r = 0; r < 4; ++r) {
    int u = w * 16 + grp * 4 + r;
    float wv = __shfl(wubacc, u & 63);
    bool val = (u < UU);
    vwr[r]  = val ? vw[u] : 0.f;
    wubr[r] = val ? wv : 0.f;
  }

  __syncthreads();   // B0: zero-fill visible

  float* outb = out + (size_t)b * NSENT * DD;

  #pragma unroll 1
  for (int t = 0; t < NSENT; ++t) {
    unsigned char* hc = (unsigned char*)&hs[t & 1][0];

    // ---- convert tile t (stage regs) -> bf16 LDS via v_cvt_pk ----
    #pragma unroll
    for (int j = 0; j < 4; ++j) {
      int idx = j * 256 + tid;
      if (idx < 1000) {
        unsigned o0, o1;
        asm("v_cvt_pk_bf16_f32 %0, %1, %2" : "=v"(o0) : "v"(stage[j].x), "v"(stage[j].y));
        asm("v_cvt_pk_bf16_f32 %0, %1, %2" : "=v"(o1) : "v"(stage[j].z), "v"(stage[j].w));
        uint2 wv; wv.x = o0; wv.y = o1;
        *(uint2*)(hc + cvta[j]) = wv;
      }
    }
    __syncthreads();   // B1

    // ---- issue tile t+1 loads (regs), pinned before compute ----
    if (t + 1 < NSENT) {
      const float4* nb4 = base4 + (size_t)(t + 1) * 1000;
      #pragma unroll
      for (int j = 0; j < 4; ++j) {
        int idx = j * 256 + tid;
        if (idx < 1000) stage[j] = nb4[idx];
      }
    }
    __builtin_amdgcn_sched_barrier(0);

    // ---- MFMA: acc[st] = C[u-tile w][s-tile st] ----
    f32x4 acc[3];
    #pragma unroll
    for (int st = 0; st < 3; ++st) { f32x4 z = {0.f,0.f,0.f,0.f}; acc[st] = z; }
    #pragma unroll
    for (int kt = 0; kt < 4; ++kt) {
      #pragma unroll
      for (int st = 0; st < 3; ++st) {
        bf16x8 hf = *(const bf16x8*)(hc + (st * 16 + col) * 272 + kt * 64 + grp * 16);
        acc[st] = __builtin_amdgcn_mfma_f32_16x16x32_bf16(afrag[kt], hf, acc[st], 0, 0, 0);
      }
    }

    // ---- partial e[s]: sum over this wave's u rows (no clamp needed) ----
    #pragma unroll
    for (int st = 0; st < 3; ++st) {
      float s = 0.f;
      #pragma unroll
      for (int r = 0; r < 4; ++r) {
        float x = acc[st][r] + wubr[r];
        float E = __expf(2.f * x);
        float tt = 1.f - 2.f * __builtin_amdgcn_rcpf(E + 1.f);
        s = fmaf(tt, vwr[r], s);
      }
      s += __shfl_xor(s, 16);
      s += __shfl_xor(s, 32);
      if (grp == 0) epart[st * 64 + col * 4 + w] = s;
    }
    __syncthreads();   // B2

    // ---- softmax over s<40 (redundant per wave; alpha ends in lane s) ----
    int sl = lane < SEC ? lane : 0;
    f32x4 q = *(const f32x4*)&epart[(sl >> 4) * 64 + (sl & 15) * 4];
    float e = (q[0] + q[1]) + (q[2] + q[3]);
    float p = (lane < SEC) ? __expf(e) : 0.f;
    float sum = p;
    sum += __shfl_xor(sum, 1);
    sum += __shfl_xor(sum, 2);
    sum += __shfl_xor(sum, 4);
    sum += __shfl_xor(sum, 8);
    sum += __shfl_xor(sum, 16);
    sum += __shfl_xor(sum, 32);
    float pr = p * __builtin_amdgcn_rcpf(sum);   // alpha[s] in lane s
    // PIN: force pr to be computed with full exec mask (all lanes) BEFORE the
    // divergent out-phase below. Without this the compiler may sink the final
    // multiply into `if (lane < 25)`, leaving lanes 25..39 stale for readlane
    // (R6 bug: absmax 26).
    asm volatile("" : "+v"(pr));

    // ---- out: wave w owns d in [25w, 25w+25); alpha via readlane ----
    if (lane < 25) {
      int d = 25 * w + lane;
      const unsigned short* hp = (const unsigned short*)hc + d;
      float a0 = 0.f, a1 = 0.f;
      #pragma unroll
      for (int s = 0; s < SEC; s += 2) {
        float al0 = __uint_as_float(__builtin_amdgcn_readlane(__float_as_uint(pr), s));
        float al1 = __uint_as_float(__builtin_amdgcn_readlane(__float_as_uint(pr), s + 1));
        a0 = fmaf(al0, __uint_as_float((unsigned)hp[s * STRIDE] << 16), a0);
        a1 = fmaf(al1, __uint_as_float((unsigned)hp[(s + 1) * STRIDE] << 16), a1);
      }
      outb[t * DD + d] = a0 + a1;
    }
    // no end barrier: buf[t&1] is next written at convert(t+2), which is
    // behind B1(t+1); epart next written behind B1(t+1) as well.
  }
}

extern "C" void kernel_launch(void* const* d_in, const int* in_sizes, int n_in,
                              void* d_out, int out_size, void* d_ws, size_t ws_size,
                              hipStream_t stream) {
  const float* inputs = (const float*)d_in[0];
  const float* vw     = (const float*)d_in[1];
  const float* wh     = (const float*)d_in[2];
  const float* wu     = (const float*)d_in[3];
  const float* bw     = (const float*)d_in[4];
  float* out = (float*)d_out;

  doc_kernel<<<NB, 256, 0, stream>>>(inputs, vw, wh, wu, bw, out);
}

// Round 8
// 161.960 us; speedup vs baseline: 1.5866x; 1.0610x over previous
//
#include <hip/hip_runtime.h>
#include <hip/hip_bf16.h>
#include <stdint.h>

#define NB    2048
#define NSENT 20
#define SEC   40
#define DD    100
#define UU    50
#define SP1   801
#define STRIDE 136   // shorts per LDS h row; 272 B

typedef short bf16x8 __attribute__((ext_vector_type(8)));
typedef float f32x4 __attribute__((ext_vector_type(4)));

__device__ __forceinline__ unsigned f2bf(float f) {
  unsigned u = __float_as_uint(f);
  return (u + 0x7fffu + ((u >> 16) & 1u)) >> 16;   // RNE
}

// One 4-wave block per document b. Wave w owns u-tile w of C[u][s] = wh·h^T.
// Depth-2 register prefetch pipeline: stage sets stA/stB alternate; convert(t)
// waits only its own loads (counted vmcnt) while t+1's stay in flight and
// t+2's are issued before the barrier. 2 barriers/tile, dbuf LDS.
__global__ __launch_bounds__(256, 4) void doc_kernel(
    const float* __restrict__ inputs, const float* __restrict__ vw,
    const float* __restrict__ wh, const float* __restrict__ wu,
    const float* __restrict__ bw, float* __restrict__ out) {
  __shared__ __align__(16) unsigned short hs[2][48 * STRIDE]; // bf16 h tiles
  __shared__ __align__(16) float epart[3 * 16 * 4];           // [st][col][w]

  const int tid  = threadIdx.x;
  const int w    = tid >> 6, lane = tid & 63;
  const int col  = lane & 15, grp = lane >> 4;
  const int b    = blockIdx.x;

  const float4* base4 = (const float4*)(inputs + (size_t)b * SP1 * DD);

  // ---- depth-2 prologue: issue tile 0 -> stA, tile 1 -> stB (no guards;
  // overshoot granules stay inside this document, junk rows are benign) ----
  float4 stA[4], stB[4];
  #pragma unroll
  for (int j = 0; j < 4; ++j) stA[j] = base4[j * 256 + tid];
  #pragma unroll
  for (int j = 0; j < 4; ++j) stB[j] = base4[1000 + j * 256 + tid];

  // ---- zero both h buffers once (K-pad cols persist; junk rows 40..47 ok) ----
  {
    uint4 z; z.x = z.y = z.z = z.w = 0u;
    uint4* p = (uint4*)&hs[0][0];
    #pragma unroll 1
    for (int i = tid; i < 2 * 48 * STRIDE / 8; i += 256) p[i] = z;
  }

  // ---- convert-pass byte addresses (fixed per thread) ----
  int cvta[4];
  #pragma unroll
  for (int j = 0; j < 4; ++j) {
    int idx = j * 256 + tid;
    int row = idx / 25, c4 = idx - row * 25;
    cvta[j] = row * 272 + c4 * 8;
  }

  // ---- A fragments: this wave's 16 wh rows (u = 16w + col), resident ----
  bf16x8 afrag[4];
  {
    int u = w * 16 + col;
    #pragma unroll
    for (int kt = 0; kt < 4; ++kt) {
      bf16x8 f;
      #pragma unroll
      for (int j = 0; j < 8; ++j) {
        int k = kt * 32 + grp * 8 + j;
        float v = (u < UU && k < DD) ? wh[u * DD + k] : 0.f;
        f[j] = (short)f2bf(v);
      }
      afrag[kt] = f;
    }
  }

  // ---- wub[u=lane] = uvec[b]·wu[u] + bw[u] (each wave redundantly) ----
  float wubacc;
  {
    int ur = lane < UU ? lane : UU - 1;
    const float4* uv4 = (const float4*)(inputs + ((size_t)b * SP1 + SP1 - 1) * DD);
    const float4* wr4 = (const float4*)(wu + ur * DD);
    float a0 = bw[ur];
    #pragma unroll 5
    for (int q = 0; q < 25; ++q) {
      float4 uq = uv4[q], wq = wr4[q];
      a0 = fmaf(uq.x, wq.x, a0); a0 = fmaf(uq.y, wq.y, a0);
      a0 = fmaf(uq.z, wq.z, a0); a0 = fmaf(uq.w, wq.w, a0);
    }
    wubacc = a0;
  }
  float vwr[4], wubr[4];
  #pragma unroll
  for (int r = 0; r < 4; ++r) {
    int u = w * 16 + grp * 4 + r;
    float wv = __shfl(wubacc, u & 63);
    bool val = (u < UU);
    vwr[r]  = val ? vw[u] : 0.f;
    wubr[r] = val ? wv : 0.f;
  }

  __syncthreads();   // B0: zero-fill visible

  float* outb = out + (size_t)b * NSENT * DD;

#define TILE_BODY(stg, t)                                                      \
  {                                                                            \
    unsigned char* hc = (unsigned char*)&hs[(t) & 1][0];                       \
    /* convert tile t (stage regs) -> bf16 LDS via v_cvt_pk */                 \
    _Pragma("unroll")                                                          \
    for (int j = 0; j < 4; ++j) {                                              \
      unsigned o0, o1;                                                         \
      asm("v_cvt_pk_bf16_f32 %0, %1, %2" : "=v"(o0) : "v"(stg[j].x), "v"(stg[j].y)); \
      asm("v_cvt_pk_bf16_f32 %0, %1, %2" : "=v"(o1) : "v"(stg[j].z), "v"(stg[j].w)); \
      uint2 wv; wv.x = o0; wv.y = o1;                                          \
      *(uint2*)(hc + cvta[j]) = wv;                                            \
    }                                                                          \
    /* issue tile t+2 loads into the stage regs just freed (WAR via order) */  \
    if ((t) + 2 < NSENT) {                                                     \
      const float4* nb4 = base4 + (size_t)((t) + 2) * 1000;                    \
      _Pragma("unroll")                                                        \
      for (int j = 0; j < 4; ++j) stg[j] = nb4[j * 256 + tid];                 \
    }                                                                          \
    __builtin_amdgcn_sched_barrier(0);                                         \
    __syncthreads(); /* B1 */                                                  \
    /* MFMA: acc[st] = C[u-tile w][s-tile st] */                               \
    f32x4 acc[3];                                                              \
    _Pragma("unroll")                                                          \
    for (int st = 0; st < 3; ++st) { f32x4 z = {0.f,0.f,0.f,0.f}; acc[st] = z; } \
    _Pragma("unroll")                                                          \
    for (int kt = 0; kt < 4; ++kt) {                                           \
      _Pragma("unroll")                                                        \
      for (int st = 0; st < 3; ++st) {                                         \
        bf16x8 hf = *(const bf16x8*)(hc + (st * 16 + col) * 272 + kt * 64 + grp * 16); \
        acc[st] = __builtin_amdgcn_mfma_f32_16x16x32_bf16(afrag[kt], hf, acc[st], 0, 0, 0); \
      }                                                                        \
    }                                                                          \
    /* partial e[s]: sum over this wave's u rows */                            \
    _Pragma("unroll")                                                          \
    for (int st = 0; st < 3; ++st) {                                           \
      float s = 0.f;                                                           \
      _Pragma("unroll")                                                        \
      for (int r = 0; r < 4; ++r) {                                            \
        float x = acc[st][r] + wubr[r];                                        \
        float E = __expf(2.f * x);                                             \
        float tt = 1.f - 2.f * __builtin_amdgcn_rcpf(E + 1.f);                 \
        s = fmaf(tt, vwr[r], s);                                               \
      }                                                                        \
      s += __shfl_xor(s, 16);                                                  \
      s += __shfl_xor(s, 32);                                                  \
      if (grp == 0) epart[st * 64 + col * 4 + w] = s;                          \
    }                                                                          \
    __syncthreads(); /* B2 */                                                  \
    /* softmax over s<40 (redundant per wave; alpha ends in lane s) */         \
    int sl = lane < SEC ? lane : 0;                                            \
    f32x4 q = *(const f32x4*)&epart[(sl >> 4) * 64 + (sl & 15) * 4];           \
    float e = (q[0] + q[1]) + (q[2] + q[3]);                                   \
    float p = (lane < SEC) ? __expf(e) : 0.f;                                  \
    float sum = p;                                                             \
    sum += __shfl_xor(sum, 1);                                                 \
    sum += __shfl_xor(sum, 2);                                                 \
    sum += __shfl_xor(sum, 4);                                                 \
    sum += __shfl_xor(sum, 8);                                                 \
    sum += __shfl_xor(sum, 16);                                                \
    sum += __shfl_xor(sum, 32);                                                \
    float pr = p * __builtin_amdgcn_rcpf(sum);                                 \
    /* PIN: compute pr with full exec mask before divergent readlane use */    \
    asm volatile("" : "+v"(pr));                                               \
    /* out: wave w owns d in [25w, 25w+25); alpha via readlane */              \
    if (lane < 25) {                                                           \
      int d = 25 * w + lane;                                                   \
      const unsigned short* hp = (const unsigned short*)hc + d;                \
      float a0 = 0.f, a1 = 0.f;                                                \
      _Pragma("unroll")                                                        \
      for (int s = 0; s < SEC; s += 2) {                                       \
        float al0 = __uint_as_float(__builtin_amdgcn_readlane(__float_as_uint(pr), s));     \
        float al1 = __uint_as_float(__builtin_amdgcn_readlane(__float_as_uint(pr), s + 1)); \
        a0 = fmaf(al0, __uint_as_float((unsigned)hp[s * STRIDE] << 16), a0);   \
        a1 = fmaf(al1, __uint_as_float((unsigned)hp[(s + 1) * STRIDE] << 16), a1); \
      }                                                                        \
      outb[(t) * DD + d] = a0 + a1;                                            \
    }                                                                          \
  }

  #pragma unroll 1
  for (int t = 0; t < NSENT; t += 2) {
    TILE_BODY(stA, t)
    TILE_BODY(stB, t + 1)
  }
#undef TILE_BODY
}

extern "C" void kernel_launch(void* const* d_in, const int* in_sizes, int n_in,
                              void* d_out, int out_size, void* d_ws, size_t ws_size,
                              hipStream_t stream) {
  const float* inputs = (const float*)d_in[0];
  const float* vw     = (const float*)d_in[1];
  const float* wh     = (const float*)d_in[2];
  const float* wu     = (const float*)d_in[3];
  const float* bw     = (const float*)d_in[4];
  float* out = (float*)d_out;

  doc_kernel<<<NB, 256, 0, stream>>>(inputs, vw, wh, wu, bw, out);
}

// Round 9
// 155.306 us; speedup vs baseline: 1.6546x; 1.0428x over previous
//
#include <hip/hip_runtime.h>
#include <hip/hip_bf16.h>
#include <stdint.h>

#define NB    2048
#define NSENT 20
#define SEC   40
#define DD    100
#define UU    50
#define SP1   801
#define STRIDE 136      // shorts per LDS h row; 272 B
#define TROWS 80        // rows per tile = 2 sentences
#define TGRAN 2000      // 16B granules per tile (80*100*4/16)
#define MAXG  20024     // last valid granule inside one document

typedef short bf16x8 __attribute__((ext_vector_type(8)));
typedef float f32x4 __attribute__((ext_vector_type(4)));

__device__ __forceinline__ unsigned f2bf(float f) {
  unsigned u = __float_as_uint(f);
  return (u + 0x7fffu + ((u >> 16) & 1u)) >> 16;   // RNE
}

// One 4-wave block per document b; each iteration covers TWO sentences
// (80 h rows). Wave w owns u-tile w of C[u][s]=wh·h^T over all 5 s-tiles.
// Softmax: waves 0,1 -> sentence A; waves 2,3 -> sentence B (parallel).
// Depth-2 register prefetch (stA/stB), dbuf LDS, 2 barriers per 2 sentences.
__global__ __launch_bounds__(256, 3) void doc_kernel(
    const float* __restrict__ inputs, const float* __restrict__ vw,
    const float* __restrict__ wh, const float* __restrict__ wu,
    const float* __restrict__ bw, float* __restrict__ out) {
  __shared__ __align__(16) unsigned short hs[2][TROWS * STRIDE]; // 2x21760 B
  __shared__ __align__(16) float epart[5 * 16 * 4];              // [st][col][w]

  const int tid  = threadIdx.x;
  const int w    = tid >> 6, lane = tid & 63;
  const int col  = lane & 15, grp = lane >> 4;
  const int b    = blockIdx.x;

  const float4* base4 = (const float4*)(inputs + (size_t)b * SP1 * DD);

  // ---- depth-2 prologue: tile 0 -> stA, tile 1 -> stB (clamped granules) ----
  float4 stA[8], stB[8];
  #pragma unroll
  for (int j = 0; j < 8; ++j) stA[j] = base4[min(j * 256 + tid, MAXG)];
  #pragma unroll
  for (int j = 0; j < 8; ++j) stB[j] = base4[min(TGRAN + j * 256 + tid, MAXG)];

  // ---- zero both h buffers once (K-pad cols 100..135 persist) ----
  {
    uint4 z; z.x = z.y = z.z = z.w = 0u;
    uint4* p = (uint4*)&hs[0][0];
    #pragma unroll 1
    for (int i = tid; i < 2 * TROWS * STRIDE / 8; i += 256) p[i] = z;
  }

  // ---- convert-pass byte addresses (fixed per thread) ----
  int cvta[8];
  #pragma unroll
  for (int j = 0; j < 8; ++j) {
    int idx = j * 256 + tid;
    int row = idx / 25, c4 = idx - row * 25;
    cvta[j] = row * 272 + c4 * 8;
  }

  // ---- A fragments: this wave's 16 wh rows (u = 16w + col), resident ----
  bf16x8 afrag[4];
  {
    int u = w * 16 + col;
    #pragma unroll
    for (int kt = 0; kt < 4; ++kt) {
      bf16x8 f;
      #pragma unroll
      for (int j = 0; j < 8; ++j) {
        int k = kt * 32 + grp * 8 + j;
        float v = (u < UU && k < DD) ? wh[u * DD + k] : 0.f;
        f[j] = (short)f2bf(v);
      }
      afrag[kt] = f;
    }
  }

  // ---- wub[u=lane] = uvec[b]·wu[u] + bw[u] (each wave redundantly) ----
  float wubacc;
  {
    int ur = lane < UU ? lane : UU - 1;
    const float4* uv4 = (const float4*)(inputs + ((size_t)b * SP1 + SP1 - 1) * DD);
    const float4* wr4 = (const float4*)(wu + ur * DD);
    float a0 = bw[ur];
    #pragma unroll 5
    for (int q = 0; q < 25; ++q) {
      float4 uq = uv4[q], wq = wr4[q];
      a0 = fmaf(uq.x, wq.x, a0); a0 = fmaf(uq.y, wq.y, a0);
      a0 = fmaf(uq.z, wq.z, a0); a0 = fmaf(uq.w, wq.w, a0);
    }
    wubacc = a0;
  }
  float vwr[4], wubr[4];
  #pragma unroll
  for (int r = 0; r < 4; ++r) {
    int u = w * 16 + grp * 4 + r;
    float wv = __shfl(wubacc, u & 63);
    bool val = (u < UU);
    vwr[r]  = val ? vw[u] : 0.f;
    wubr[r] = val ? wv : 0.f;
  }

  __syncthreads();   // B0: zero-fill visible

  float* outb = out + (size_t)b * NSENT * DD;
  const int sent = w >> 1, dh = w & 1;      // out-phase roles

#define TILE_BODY(stg, t)                                                      \
  {                                                                            \
    unsigned char* hc = (unsigned char*)&hs[(t) & 1][0];                       \
    /* convert tile t (stage regs) -> bf16 LDS via v_cvt_pk */                 \
    _Pragma("unroll")                                                          \
    for (int j = 0; j < 8; ++j) {                                              \
      int idx = j * 256 + tid;                                                 \
      if (j < 7 || idx < TGRAN) {                                              \
        unsigned o0, o1;                                                       \
        asm("v_cvt_pk_bf16_f32 %0, %1, %2" : "=v"(o0) : "v"(stg[j].x), "v"(stg[j].y)); \
        asm("v_cvt_pk_bf16_f32 %0, %1, %2" : "=v"(o1) : "v"(stg[j].z), "v"(stg[j].w)); \
        uint2 wv; wv.x = o0; wv.y = o1;                                        \
        *(uint2*)(hc + cvta[j]) = wv;                                          \
      }                                                                        \
    }                                                                          \
    /* issue tile t+2 loads into the freed stage regs */                       \
    if ((t) + 2 < NSENT / 2) {                                                 \
      _Pragma("unroll")                                                        \
      for (int j = 0; j < 8; ++j)                                              \
        stg[j] = base4[min(((t) + 2) * TGRAN + j * 256 + tid, MAXG)];          \
    }                                                                          \
    __builtin_amdgcn_sched_barrier(0);                                         \
    __syncthreads(); /* B1 */                                                  \
    /* MFMA: acc[st] = C[u-tile w][s-tile st], st 0..4 */                      \
    f32x4 acc[5];                                                              \
    _Pragma("unroll")                                                          \
    for (int st = 0; st < 5; ++st) { f32x4 z = {0.f,0.f,0.f,0.f}; acc[st] = z; } \
    _Pragma("unroll")                                                          \
    for (int kt = 0; kt < 4; ++kt) {                                           \
      _Pragma("unroll")                                                        \
      for (int st = 0; st < 5; ++st) {                                         \
        bf16x8 hf = *(const bf16x8*)(hc + (st * 16 + col) * 272 + kt * 64 + grp * 16); \
        acc[st] = __builtin_amdgcn_mfma_f32_16x16x32_bf16(afrag[kt], hf, acc[st], 0, 0, 0); \
      }                                                                        \
    }                                                                          \
    /* partial e[s]: sum over this wave's u rows */                            \
    _Pragma("unroll")                                                          \
    for (int st = 0; st < 5; ++st) {                                           \
      float s = 0.f;                                                           \
      _Pragma("unroll")                                                        \
      for (int r = 0; r < 4; ++r) {                                            \
        float x = acc[st][r] + wubr[r];                                        \
        float E = __expf(2.f * x);                                             \
        float tt = 1.f - 2.f * __builtin_amdgcn_rcpf(E + 1.f);                 \
        s = fmaf(tt, vwr[r], s);                                               \
      }                                                                        \
      s += __shfl_xor(s, 16);                                                  \
      s += __shfl_xor(s, 32);                                                  \
      if (grp == 0) epart[st * 64 + col * 4 + w] = s;                          \
    }                                                                          \
    __syncthreads(); /* B2 */                                                  \
    /* softmax: this wave's sentence (waves 0,1->A; 2,3->B), 40 values */      \
    int srow = sent * SEC + (lane < SEC ? lane : 0);                           \
    f32x4 q = *(const f32x4*)&epart[(srow >> 4) * 64 + (srow & 15) * 4];       \
    float e = (q[0] + q[1]) + (q[2] + q[3]);                                   \
    float p = (lane < SEC) ? __expf(e) : 0.f;                                  \
    float sum = p;                                                             \
    sum += __shfl_xor(sum, 1);                                                 \
    sum += __shfl_xor(sum, 2);                                                 \
    sum += __shfl_xor(sum, 4);                                                 \
    sum += __shfl_xor(sum, 8);                                                 \
    sum += __shfl_xor(sum, 16);                                                \
    sum += __shfl_xor(sum, 32);                                                \
    float pr = p * __builtin_amdgcn_rcpf(sum);                                 \
    /* PIN: compute pr with full exec mask before divergent readlane use */    \
    asm volatile("" : "+v"(pr));                                               \
    /* out: wave w -> sentence sent, d-half dh (50 d's); alpha via readlane */ \
    if (lane < 50) {                                                           \
      int d = dh * 50 + lane;                                                  \
      const unsigned short* hp = (const unsigned short*)hc + sent * SEC * STRIDE + d; \
      float a0 = 0.f, a1 = 0.f;                                                \
      _Pragma("unroll")                                                        \
      for (int s = 0; s < SEC; s += 2) {                                       \
        float al0 = __uint_as_float(__builtin_amdgcn_readlane(__float_as_uint(pr), s));     \
        float al1 = __uint_as_float(__builtin_amdgcn_readlane(__float_as_uint(pr), s + 1)); \
        a0 = fmaf(al0, __uint_as_float((unsigned)hp[s * STRIDE] << 16), a0);   \
        a1 = fmaf(al1, __uint_as_float((unsigned)hp[(s + 1) * STRIDE] << 16), a1); \
      }                                                                        \
      outb[((t) * 2 + sent) * DD + d] = a0 + a1;                               \
    }                                                                          \
  }

  #pragma unroll 1
  for (int t = 0; t < NSENT / 2; t += 2) {
    TILE_BODY(stA, t)
    TILE_BODY(stB, t + 1)
  }
#undef TILE_BODY
}

extern "C" void kernel_launch(void* const* d_in, const int* in_sizes, int n_in,
                              void* d_out, int out_size, void* d_ws, size_t ws_size,
                              hipStream_t stream) {
  const float* inputs = (const float*)d_in[0];
  const float* vw     = (const float*)d_in[1];
  const float* wh     = (const float*)d_in[2];
  const float* wu     = (const float*)d_in[3];
  const float* bw     = (const float*)d_in[4];
  float* out = (float*)d_out;

  doc_kernel<<<NB, 256, 0, stream>>>(inputs, vw, wh, wu, bw, out);
}